// Round 9
// baseline (303.500 us; speedup 1.0000x reference)
//
#include <hip/hip_runtime.h>

typedef __bf16 bf16;
typedef __bf16 bfx8 __attribute__((ext_vector_type(8)));
typedef __bf16 bfx4 __attribute__((ext_vector_type(4)));
typedef float f32x4 __attribute__((ext_vector_type(4)));

#define MFMA_BF16 __builtin_amdgcn_mfma_f32_16x16x32_bf16

static constexpr int Bq = 4, Sq = 2048, Dq = 1024, Hq = 16, HDq = 64;
static constexpr int Mq = Bq * Sq;          // 8192
static constexpr int D3 = 3 * Dq;           // 3072
static constexpr float L2E = 1.4426950408889634f;
static constexpr float QSC = 0.125f * L2E;  // softmax scale folded into Q

typedef const __attribute__((address_space(1))) void* gas1;
typedef __attribute__((address_space(3))) void* las3;

__device__ __forceinline__ void gload_lds16(const bf16* g, bf16* l) {
    __builtin_amdgcn_global_load_lds((gas1)g, (las3)l, 16, 0, 0);
}

__device__ __forceinline__ float fast_exp2(float x) {
    return __builtin_amdgcn_exp2f(x);
}

// ---------------- cast x: fp32 -> bf16 ----------------
__global__ __launch_bounds__(256) void cast_f32_bf16(const float* __restrict__ in,
                                                     bf16* __restrict__ out, int n) {
    int i = (blockIdx.x * 256 + threadIdx.x) * 4;
    if (i + 3 < n) {
        float4 v = *(const float4*)(in + i);
        bfx4 r;
        r[0] = (bf16)v.x; r[1] = (bf16)v.y; r[2] = (bf16)v.z; r[3] = (bf16)v.w;
        *(bfx4*)(out + i) = r;
    }
}

// ---------------- transpose+cast: in fp32 [R][C] -> out bf16 [C][R] ----------------
__global__ __launch_bounds__(256) void transpose_cast(const float* __restrict__ in,
                                                      bf16* __restrict__ out, int R, int C) {
    __shared__ float tile[32][33];
    int tx = threadIdx.x, ty = threadIdx.y;     // 32 x 8
    int c0 = blockIdx.x * 32, r0 = blockIdx.y * 32;
    for (int j = 0; j < 32; j += 8)
        tile[ty + j][tx] = in[(size_t)(r0 + ty + j) * C + c0 + tx];
    __syncthreads();
    for (int j = 0; j < 32; j += 8)
        out[(size_t)(c0 + ty + j) * R + r0 + tx] = (bf16)tile[tx][ty + j];
}

// ---------------- V transpose: qkv V-part [b][s][hd] -> Vt [b][hd][s] (bf16) ----------------
__global__ __launch_bounds__(256) void vtrans(const bf16* __restrict__ qkv,
                                              bf16* __restrict__ Vt) {
    __shared__ bf16 tile[32][33];
    int tx = threadIdx.x, ty = threadIdx.y;     // 32 x 8
    int c0 = blockIdx.x * 32;                   // hd (V column) 0..1023
    int s0 = blockIdx.y * 32;                   // s
    int b = blockIdx.z;
    for (int j = 0; j < 32; j += 8)
        tile[ty + j][tx] = qkv[(size_t)(b * Sq + s0 + ty + j) * D3 + 2 * Dq + c0 + tx];
    __syncthreads();
    for (int j = 0; j < 32; j += 8)
        Vt[((size_t)b * Dq + c0 + ty + j) * Sq + s0 + tx] = tile[tx][ty + j];
}

// ---------------- GEMM 128x128: C[M,N] = A[M,K] * Bt[N,K]^T ----------------
template <bool OUT_F32, bool QSCALE>
__global__ __launch_bounds__(256) void gemm_bt(const bf16* __restrict__ A,
                                               const bf16* __restrict__ Bt,
                                               void* __restrict__ Cout,
                                               int M, int N, int K) {
    __shared__ bf16 As[128 * 64];
    __shared__ bf16 Bs[128 * 64];
    int m0 = blockIdx.y * 128;
    int n0 = blockIdx.x * 128;
    int tid = threadIdx.x;
    int lane = tid & 63, wave = tid >> 6;
    int quad = lane >> 4, l16 = lane & 15;
    int wr = wave >> 1, wc = wave & 1;
    int sw = l16 & 7;

    f32x4 acc[4][4] = {};

    for (int k0 = 0; k0 < K; k0 += 64) {
        __syncthreads();
        #pragma unroll
        for (int i = 0; i < 4; i++) {
            int c = i * 256 + tid;
            int row = c >> 3;
            int ch = (c & 7) ^ (row & 7);
            gload_lds16(A + (size_t)(m0 + row) * K + k0 + ch * 8, As + c * 8);
            gload_lds16(Bt + (size_t)(n0 + row) * K + k0 + ch * 8, Bs + c * 8);
        }
        __syncthreads();
        #pragma unroll
        for (int s = 0; s < 2; s++) {
            bfx8 af[4], bfr[4];
            #pragma unroll
            for (int i = 0; i < 4; i++)
                af[i] = *(const bfx8*)(As + (wr * 64 + i * 16 + l16) * 64 +
                                       ((s * 4 + quad) ^ sw) * 8);
            #pragma unroll
            for (int j = 0; j < 4; j++)
                bfr[j] = *(const bfx8*)(Bs + (wc * 64 + j * 16 + l16) * 64 +
                                        ((s * 4 + quad) ^ sw) * 8);
            #pragma unroll
            for (int i = 0; i < 4; i++)
                #pragma unroll
                for (int j = 0; j < 4; j++)
                    acc[i][j] = MFMA_BF16(af[i], bfr[j], acc[i][j], 0, 0, 0);
        }
    }

    #pragma unroll
    for (int i = 0; i < 4; i++)
        #pragma unroll
        for (int j = 0; j < 4; j++) {
            int col = n0 + wc * 64 + j * 16 + l16;
            float scale = (QSCALE && col < Dq) ? QSC : 1.0f;
            #pragma unroll
            for (int r = 0; r < 4; r++) {
                int row = m0 + wr * 64 + i * 16 + quad * 4 + r;
                if (OUT_F32)
                    ((float*)Cout)[(size_t)row * N + col] = acc[i][j][r];
                else
                    ((bf16*)Cout)[(size_t)row * N + col] = (bf16)(acc[i][j][r] * scale);
            }
        }
}

// ---------------- GEMM 128x64 tiles (for N=1024: grid 1024 blocks = 4/CU) ----------
__global__ __launch_bounds__(256) void gemm_bt_n64(const bf16* __restrict__ A,
                                                   const bf16* __restrict__ Bt,
                                                   float* __restrict__ Cout,
                                                   int M, int N, int K) {
    __shared__ bf16 As[128 * 64];
    __shared__ bf16 Bs[64 * 64];
    int m0 = blockIdx.y * 128;
    int n0 = blockIdx.x * 64;
    int tid = threadIdx.x;
    int lane = tid & 63, wave = tid >> 6;
    int quad = lane >> 4, l16 = lane & 15;
    int wr = wave >> 1, wc = wave & 1;     // wave tile: 64M x 32N
    int sw = l16 & 7;

    f32x4 acc[4][2] = {};

    for (int k0 = 0; k0 < K; k0 += 64) {
        __syncthreads();
        #pragma unroll
        for (int i = 0; i < 4; i++) {
            int c = i * 256 + tid;
            int row = c >> 3;
            int ch = (c & 7) ^ (row & 7);
            gload_lds16(A + (size_t)(m0 + row) * K + k0 + ch * 8, As + c * 8);
        }
        #pragma unroll
        for (int i = 0; i < 2; i++) {
            int c = i * 256 + tid;
            int row = c >> 3;
            int ch = (c & 7) ^ (row & 7);
            gload_lds16(Bt + (size_t)(n0 + row) * K + k0 + ch * 8, Bs + c * 8);
        }
        __syncthreads();
        #pragma unroll
        for (int s = 0; s < 2; s++) {
            bfx8 af[4], bfr[2];
            #pragma unroll
            for (int i = 0; i < 4; i++)
                af[i] = *(const bfx8*)(As + (wr * 64 + i * 16 + l16) * 64 +
                                       ((s * 4 + quad) ^ sw) * 8);
            #pragma unroll
            for (int j = 0; j < 2; j++)
                bfr[j] = *(const bfx8*)(Bs + (wc * 32 + j * 16 + l16) * 64 +
                                        ((s * 4 + quad) ^ sw) * 8);
            #pragma unroll
            for (int i = 0; i < 4; i++)
                #pragma unroll
                for (int j = 0; j < 2; j++)
                    acc[i][j] = MFMA_BF16(af[i], bfr[j], acc[i][j], 0, 0, 0);
        }
    }

    #pragma unroll
    for (int i = 0; i < 4; i++)
        #pragma unroll
        for (int j = 0; j < 2; j++) {
            int col = n0 + wc * 32 + j * 16 + l16;
            #pragma unroll
            for (int r = 0; r < 4; r++) {
                int row = m0 + wr * 64 + i * 16 + quad * 4 + r;
                Cout[(size_t)row * N + col] = acc[i][j][r];
            }
        }
}

// ---------------- Flash attention: permuted-K staging -> register P in K=32 layout --
// 1024 blocks; block = 2 waves (128 thr); each wave owns 64 q rows.
// bid&7 == head&7 -> all 16 q-blocks of one head on one XCD (K/V L2 reuse).
// K staged with ROWS PERMUTED so the QK^T C-layout (key = 4*quad + r per 16-tile)
// lands exactly in the K=32 A-operand layout (key = 8*quad + j per 32-tile):
//   LDS row r <- key 32*(r>>5) + 4*((r>>4)&1) + 8*((r&15)>>2) + (r&3)
// => exp2'd P feeds PV (16x16x32) straight from registers. No Ps, no extra MFMAs.
__global__ __launch_bounds__(128, 3) void attn_kernel(const bf16* __restrict__ qkv,
                                                      const bf16* __restrict__ Vt,
                                                      bf16* __restrict__ out) {
    __shared__ bf16 Ks[2][64 * 64];
    __shared__ bf16 Vs[2][64 * 64];

    int bid = blockIdx.x;
    int head = bid & 63;                    // bid&7 == head&7
    int qc = bid >> 6;                      // 0..15
    int h = head & 15, b = head >> 4;
    int tid = threadIdx.x;                  // 0..127
    int lane = tid & 63, wave = tid >> 6;
    int quad = lane >> 4, l16 = lane & 15;
    int sw = l16 & 7;

    size_t base = (size_t)b * Sq * D3;
    const bf16* Kbase = qkv + base + Dq + h * HDq;
    const bf16* Vbase = Vt + ((size_t)b * Dq + h * HDq) * Sq;
    int q0 = qc * 128 + wave * 64;

    // Q fragments (pre-scaled by QSC in the QKV GEMM); B-layout == A-layout
    bfx8 qf[4][2];
    #pragma unroll
    for (int qt = 0; qt < 4; qt++)
        #pragma unroll
        for (int s = 0; s < 2; s++)
            qf[qt][s] = *(const bfx8*)(qkv + base + (size_t)(q0 + qt * 16 + l16) * D3 +
                                       h * HDq + s * 32 + quad * 8);

    f32x4 oacc[4][4] = {};
    float lsum[4] = {0.f, 0.f, 0.f, 0.f};

    // staging: 128 threads x 4 16B-slots per matrix; K rows permuted
    int src_r[4], src_ch[4], kperm[4];
    #pragma unroll
    for (int j = 0; j < 4; j++) {
        int c = tid + j * 128;              // LDS slot index (row = c>>3, col = c&7)
        int r = c >> 3;
        src_r[j] = r;
        src_ch[j] = (c & 7) ^ (r & 7);
        kperm[j] = 32 * (r >> 5) + 4 * ((r >> 4) & 1) + 8 * ((r & 15) >> 2) + (r & 3);
    }

    // prologue: chunk 0 -> buffer 0
    #pragma unroll
    for (int j = 0; j < 4; j++) {
        int c = tid + j * 128;
        gload_lds16(Kbase + (size_t)kperm[j] * D3 + src_ch[j] * 8, Ks[0] + c * 8);
        gload_lds16(Vbase + (size_t)src_r[j] * Sq + src_ch[j] * 8, Vs[0] + c * 8);
    }

    for (int i = 0; i < 32; i++) {
        int cur = i & 1;
        __syncthreads();   // drains prefetch into buf[cur]; fences buf[cur^1] reuse
        if (i + 1 < 32) {  // prefetch next chunk; overlaps the whole compute below
            int k0 = (i + 1) * 64;
            bf16* kd = Ks[cur ^ 1];
            bf16* vd = Vs[cur ^ 1];
            #pragma unroll
            for (int j = 0; j < 4; j++) {
                int c = tid + j * 128;
                gload_lds16(Kbase + (size_t)(k0 + kperm[j]) * D3 + src_ch[j] * 8, kd + c * 8);
                gload_lds16(Vbase + (size_t)src_r[j] * Sq + k0 + src_ch[j] * 8, vd + c * 8);
            }
        }
        const bf16* K_ = Ks[cur];
        const bf16* V_ = Vs[cur];

        #pragma unroll
        for (int kt = 0; kt < 2; kt++) {   // 32-key tiles
            bfx4 plo[4], phi[4];
            // halftile t=0: output keys 32kt + 8*quad + r
            {
                const bf16* Kh = K_ + (2 * kt) * 16 * 64;
                bfx8 k0f = *(const bfx8*)(Kh + l16 * 64 + (quad ^ sw) * 8);
                bfx8 k1f = *(const bfx8*)(Kh + l16 * 64 + ((4 + quad) ^ sw) * 8);
                #pragma unroll
                for (int qt = 0; qt < 4; qt++) {
                    f32x4 s = {};
                    s = MFMA_BF16(k0f, qf[qt][0], s, 0, 0, 0);
                    s = MFMA_BF16(k1f, qf[qt][1], s, 0, 0, 0);
                    #pragma unroll
                    for (int r = 0; r < 4; r++) {
                        float e = fast_exp2(s[r]);
                        plo[qt][r] = (bf16)e;
                        lsum[qt] += e;
                    }
                }
            }
            // halftile t=1: output keys 32kt + 8*quad + 4 + r
            {
                const bf16* Kh = K_ + (2 * kt + 1) * 16 * 64;
                bfx8 k0f = *(const bfx8*)(Kh + l16 * 64 + (quad ^ sw) * 8);
                bfx8 k1f = *(const bfx8*)(Kh + l16 * 64 + ((4 + quad) ^ sw) * 8);
                #pragma unroll
                for (int qt = 0; qt < 4; qt++) {
                    f32x4 s = {};
                    s = MFMA_BF16(k0f, qf[qt][0], s, 0, 0, 0);
                    s = MFMA_BF16(k1f, qf[qt][1], s, 0, 0, 0);
                    #pragma unroll
                    for (int r = 0; r < 4; r++) {
                        float e = fast_exp2(s[r]);
                        phi[qt][r] = (bf16)e;
                        lsum[qt] += e;
                    }
                }
            }
            // P fragment (K=32 A-layout): keys 32kt + 8*quad + {0..7}
            bfx8 p8[4];
            #pragma unroll
            for (int qt = 0; qt < 4; qt++)
                p8[qt] = __builtin_shufflevector(plo[qt], phi[qt], 0, 1, 2, 3, 4, 5, 6, 7);

            // O += P V : B-frag = V^T[d = nt*16+l16][key = 32kt + 8*quad + j]
            #pragma unroll
            for (int nt = 0; nt < 4; nt++) {
                bfx8 vf = *(const bfx8*)(V_ + (nt * 16 + l16) * 64 +
                                         ((4 * kt + quad) ^ sw) * 8);
                #pragma unroll
                for (int qt = 0; qt < 4; qt++)
                    oacc[qt][nt] = MFMA_BF16(p8[qt], vf, oacc[qt][nt], 0, 0, 0);
            }
        }
    }

    // reduce row sums across quads: lane(*, l16) gets l[q = qt*16 + l16]
    float lfull[4];
    #pragma unroll
    for (int qt = 0; qt < 4; qt++) {
        float v = lsum[qt];
        v += __shfl_xor(v, 16);
        v += __shfl_xor(v, 32);
        lfull[qt] = v;
    }

    // epilogue: O rows are q = qt*16 + quad*4 + r; l fetched from lane (quad*4+r)
    #pragma unroll
    for (int qt = 0; qt < 4; qt++)
        #pragma unroll
        for (int r = 0; r < 4; r++) {
            int row = q0 + qt * 16 + quad * 4 + r;
            float inv = 1.0f / __shfl(lfull[qt], quad * 4 + r);
            #pragma unroll
            for (int nt = 0; nt < 4; nt++)
                out[((size_t)b * Sq + row) * Dq + h * HDq + nt * 16 + l16] =
                    (bf16)(oacc[qt][nt][r] * inv);
        }
}

extern "C" void kernel_launch(void* const* d_in, const int* in_sizes, int n_in,
                              void* d_out, int out_size, void* d_ws, size_t ws_size,
                              hipStream_t stream) {
    const float* x     = (const float*)d_in[0];
    const float* w_qkv = (const float*)d_in[1];
    const float* w_out = (const float*)d_in[2];
    float* out = (float*)d_out;

    char* ws = (char*)d_ws;
    bf16* x_bf   = (bf16*)ws;                                   // 16 MB (reused as Vt later)
    bf16* wqkvT  = (bf16*)(ws + 16777216);                      //  6 MB
    bf16* woutT  = (bf16*)(ws + 16777216 + 6291456);            //  2 MB
    bf16* qkv    = (bf16*)(ws + 16777216 + 6291456 + 2097152);  // 48 MB
    bf16* attn   = (bf16*)(ws + 16777216 + 6291456 + 2097152 + 50331648); // 16 MB
    bf16* Vt     = x_bf;   // x_bf dead after gemm1; reuse for V^T

    // 1. casts
    cast_f32_bf16<<<(Mq * Dq) / 4 / 256, 256, 0, stream>>>(x, x_bf, Mq * Dq);
    dim3 tb(32, 8);
    transpose_cast<<<dim3(D3 / 32, Dq / 32), tb, 0, stream>>>(w_qkv, wqkvT, Dq, D3);
    transpose_cast<<<dim3(Dq / 32, Dq / 32), tb, 0, stream>>>(w_out, woutT, Dq, Dq);

    // 2. qkv = x @ w_qkv   [8192 x 3072], Q columns pre-scaled by 0.125*log2(e)
    gemm_bt<false, true><<<dim3(D3 / 128, Mq / 128), 256, 0, stream>>>(x_bf, wqkvT, qkv, Mq, D3, Dq);

    // 3. V transpose (x_bf dead now)
    vtrans<<<dim3(Dq / 32, Sq / 32, Bq), tb, 0, stream>>>(qkv, Vt);

    // 4. attention (1024 blocks, XCD-affine, register-P)
    attn_kernel<<<1024, 128, 0, stream>>>(qkv, Vt, attn);

    // 5. out = attn @ w_out  [8192 x 1024], fp32 out; 128x64 tiles -> 1024 blocks
    gemm_bt_n64<<<dim3(Dq / 64, Mq / 128), 256, 0, stream>>>(attn, woutT, out, Mq, Dq, Dq);
}

// Round 10
// 275.691 us; speedup vs baseline: 1.1009x; 1.1009x over previous
//
#include <hip/hip_runtime.h>

typedef __bf16 bf16;
typedef __bf16 bfx8 __attribute__((ext_vector_type(8)));
typedef __bf16 bfx4 __attribute__((ext_vector_type(4)));
typedef float f32x4 __attribute__((ext_vector_type(4)));

#define MFMA_BF16 __builtin_amdgcn_mfma_f32_16x16x32_bf16

static constexpr int Bq = 4, Sq = 2048, Dq = 1024, Hq = 16, HDq = 64;
static constexpr int Mq = Bq * Sq;          // 8192
static constexpr int D3 = 3 * Dq;           // 3072
static constexpr float L2E = 1.4426950408889634f;
static constexpr float QSC = 0.125f * L2E;  // softmax scale folded into Q

typedef const __attribute__((address_space(1))) void* gas1;
typedef __attribute__((address_space(3))) void* las3;

__device__ __forceinline__ void gload_lds16(const bf16* g, bf16* l) {
    __builtin_amdgcn_global_load_lds((gas1)g, (las3)l, 16, 0, 0);
}

__device__ __forceinline__ float fast_exp2(float x) {
    return __builtin_amdgcn_exp2f(x);
}

// ---------------- cast x: fp32 -> bf16 ----------------
__global__ __launch_bounds__(256) void cast_f32_bf16(const float* __restrict__ in,
                                                     bf16* __restrict__ out, int n) {
    int i = (blockIdx.x * 256 + threadIdx.x) * 4;
    if (i + 3 < n) {
        float4 v = *(const float4*)(in + i);
        bfx4 r;
        r[0] = (bf16)v.x; r[1] = (bf16)v.y; r[2] = (bf16)v.z; r[3] = (bf16)v.w;
        *(bfx4*)(out + i) = r;
    }
}

// ---------------- transpose+cast: in fp32 [R][C] -> out bf16 [C][R] ----------------
__global__ __launch_bounds__(256) void transpose_cast(const float* __restrict__ in,
                                                      bf16* __restrict__ out, int R, int C) {
    __shared__ float tile[32][33];
    int tx = threadIdx.x, ty = threadIdx.y;     // 32 x 8
    int c0 = blockIdx.x * 32, r0 = blockIdx.y * 32;
    for (int j = 0; j < 32; j += 8)
        tile[ty + j][tx] = in[(size_t)(r0 + ty + j) * C + c0 + tx];
    __syncthreads();
    for (int j = 0; j < 32; j += 8)
        out[(size_t)(c0 + ty + j) * R + r0 + tx] = (bf16)tile[tx][ty + j];
}

// ---------------- V transpose: qkv V-part [b][s][hd] -> Vt [b][hd][s] (bf16) ----------------
__global__ __launch_bounds__(256) void vtrans(const bf16* __restrict__ qkv,
                                              bf16* __restrict__ Vt) {
    __shared__ bf16 tile[32][33];
    int tx = threadIdx.x, ty = threadIdx.y;     // 32 x 8
    int c0 = blockIdx.x * 32;                   // hd (V column) 0..1023
    int s0 = blockIdx.y * 32;                   // s
    int b = blockIdx.z;
    for (int j = 0; j < 32; j += 8)
        tile[ty + j][tx] = qkv[(size_t)(b * Sq + s0 + ty + j) * D3 + 2 * Dq + c0 + tx];
    __syncthreads();
    for (int j = 0; j < 32; j += 8)
        Vt[((size_t)b * Dq + c0 + ty + j) * Sq + s0 + tx] = tile[tx][ty + j];
}

// ---------------- GEMM 128x128: C[M,N] = A[M,K] * Bt[N,K]^T ----------------
template <bool OUT_F32, bool QSCALE>
__global__ __launch_bounds__(256) void gemm_bt(const bf16* __restrict__ A,
                                               const bf16* __restrict__ Bt,
                                               void* __restrict__ Cout,
                                               int M, int N, int K) {
    __shared__ bf16 As[128 * 64];
    __shared__ bf16 Bs[128 * 64];
    int m0 = blockIdx.y * 128;
    int n0 = blockIdx.x * 128;
    int tid = threadIdx.x;
    int lane = tid & 63, wave = tid >> 6;
    int quad = lane >> 4, l16 = lane & 15;
    int wr = wave >> 1, wc = wave & 1;
    int sw = l16 & 7;

    f32x4 acc[4][4] = {};

    for (int k0 = 0; k0 < K; k0 += 64) {
        __syncthreads();
        #pragma unroll
        for (int i = 0; i < 4; i++) {
            int c = i * 256 + tid;
            int row = c >> 3;
            int ch = (c & 7) ^ (row & 7);
            gload_lds16(A + (size_t)(m0 + row) * K + k0 + ch * 8, As + c * 8);
            gload_lds16(Bt + (size_t)(n0 + row) * K + k0 + ch * 8, Bs + c * 8);
        }
        __syncthreads();
        #pragma unroll
        for (int s = 0; s < 2; s++) {
            bfx8 af[4], bfr[4];
            #pragma unroll
            for (int i = 0; i < 4; i++)
                af[i] = *(const bfx8*)(As + (wr * 64 + i * 16 + l16) * 64 +
                                       ((s * 4 + quad) ^ sw) * 8);
            #pragma unroll
            for (int j = 0; j < 4; j++)
                bfr[j] = *(const bfx8*)(Bs + (wc * 64 + j * 16 + l16) * 64 +
                                        ((s * 4 + quad) ^ sw) * 8);
            #pragma unroll
            for (int i = 0; i < 4; i++)
                #pragma unroll
                for (int j = 0; j < 4; j++)
                    acc[i][j] = MFMA_BF16(af[i], bfr[j], acc[i][j], 0, 0, 0);
        }
    }

    #pragma unroll
    for (int i = 0; i < 4; i++)
        #pragma unroll
        for (int j = 0; j < 4; j++) {
            int col = n0 + wc * 64 + j * 16 + l16;
            float scale = (QSCALE && col < Dq) ? QSC : 1.0f;
            #pragma unroll
            for (int r = 0; r < 4; r++) {
                int row = m0 + wr * 64 + i * 16 + quad * 4 + r;
                if (OUT_F32)
                    ((float*)Cout)[(size_t)row * N + col] = acc[i][j][r];
                else
                    ((bf16*)Cout)[(size_t)row * N + col] = (bf16)(acc[i][j][r] * scale);
            }
        }
}

// ---------------- GEMM 128x64 tiles (for N=1024: grid 1024 blocks = 4/CU) ----------
__global__ __launch_bounds__(256) void gemm_bt_n64(const bf16* __restrict__ A,
                                                   const bf16* __restrict__ Bt,
                                                   float* __restrict__ Cout,
                                                   int M, int N, int K) {
    __shared__ bf16 As[128 * 64];
    __shared__ bf16 Bs[64 * 64];
    int m0 = blockIdx.y * 128;
    int n0 = blockIdx.x * 64;
    int tid = threadIdx.x;
    int lane = tid & 63, wave = tid >> 6;
    int quad = lane >> 4, l16 = lane & 15;
    int wr = wave >> 1, wc = wave & 1;     // wave tile: 64M x 32N
    int sw = l16 & 7;

    f32x4 acc[4][2] = {};

    for (int k0 = 0; k0 < K; k0 += 64) {
        __syncthreads();
        #pragma unroll
        for (int i = 0; i < 4; i++) {
            int c = i * 256 + tid;
            int row = c >> 3;
            int ch = (c & 7) ^ (row & 7);
            gload_lds16(A + (size_t)(m0 + row) * K + k0 + ch * 8, As + c * 8);
        }
        #pragma unroll
        for (int i = 0; i < 2; i++) {
            int c = i * 256 + tid;
            int row = c >> 3;
            int ch = (c & 7) ^ (row & 7);
            gload_lds16(Bt + (size_t)(n0 + row) * K + k0 + ch * 8, Bs + c * 8);
        }
        __syncthreads();
        #pragma unroll
        for (int s = 0; s < 2; s++) {
            bfx8 af[4], bfr[2];
            #pragma unroll
            for (int i = 0; i < 4; i++)
                af[i] = *(const bfx8*)(As + (wr * 64 + i * 16 + l16) * 64 +
                                       ((s * 4 + quad) ^ sw) * 8);
            #pragma unroll
            for (int j = 0; j < 2; j++)
                bfr[j] = *(const bfx8*)(Bs + (wc * 32 + j * 16 + l16) * 64 +
                                        ((s * 4 + quad) ^ sw) * 8);
            #pragma unroll
            for (int i = 0; i < 4; i++)
                #pragma unroll
                for (int j = 0; j < 2; j++)
                    acc[i][j] = MFMA_BF16(af[i], bfr[j], acc[i][j], 0, 0, 0);
        }
    }

    #pragma unroll
    for (int i = 0; i < 4; i++)
        #pragma unroll
        for (int j = 0; j < 2; j++) {
            int col = n0 + wc * 32 + j * 16 + l16;
            #pragma unroll
            for (int r = 0; r < 4; r++) {
                int row = m0 + wr * 64 + i * 16 + quad * 4 + r;
                Cout[(size_t)row * N + col] = acc[i][j][r];
            }
        }
}

// ---------------- Flash attention: permuted-K staging, register P, 16 waves/CU ----
// 1024 blocks x 256 thr (4 waves); each wave owns 32 q rows (128 q/block).
// bid&7 == head&7 -> all 16 q-blocks of one head on one XCD (K/V L2 reuse).
// K staged with ROWS PERMUTED so the QK^T C-layout (key = 4*quad + r per 16-tile)
// lands exactly in the K=32 A-operand layout (key = 8*quad + j per 32-tile):
//   LDS row r <- key 32*(r>>5) + 4*((r>>4)&1) + 8*((r&15)>>2) + (r&3)
// => exp2'd P feeds PV (16x16x32) straight from registers. No Ps, no extra MFMAs,
// zero bank conflicts (verified R9).
__global__ __launch_bounds__(256, 4) void attn_kernel(const bf16* __restrict__ qkv,
                                                      const bf16* __restrict__ Vt,
                                                      bf16* __restrict__ out) {
    __shared__ bf16 Ks[2][64 * 64];
    __shared__ bf16 Vs[2][64 * 64];

    int bid = blockIdx.x;
    int head = bid & 63;                    // bid&7 == head&7
    int qc = bid >> 6;                      // 0..15
    int h = head & 15, b = head >> 4;
    int tid = threadIdx.x;                  // 0..255
    int lane = tid & 63, wave = tid >> 6;
    int quad = lane >> 4, l16 = lane & 15;
    int sw = l16 & 7;

    size_t base = (size_t)b * Sq * D3;
    const bf16* Kbase = qkv + base + Dq + h * HDq;
    const bf16* Vbase = Vt + ((size_t)b * Dq + h * HDq) * Sq;
    int q0 = qc * 128 + wave * 32;

    // Q fragments (pre-scaled by QSC in the QKV GEMM); B-layout == A-layout
    bfx8 qf[2][2];
    #pragma unroll
    for (int qt = 0; qt < 2; qt++)
        #pragma unroll
        for (int s = 0; s < 2; s++)
            qf[qt][s] = *(const bfx8*)(qkv + base + (size_t)(q0 + qt * 16 + l16) * D3 +
                                       h * HDq + s * 32 + quad * 8);

    f32x4 oacc[2][4] = {};
    float lsum[2] = {0.f, 0.f};

    // staging: 256 threads x 2 16B-slots per matrix; K rows permuted
    int src_r[2], src_ch[2], kperm[2];
    #pragma unroll
    for (int j = 0; j < 2; j++) {
        int c = tid + j * 256;              // LDS slot index (row = c>>3, col = c&7)
        int r = c >> 3;
        src_r[j] = r;
        src_ch[j] = (c & 7) ^ (r & 7);
        kperm[j] = 32 * (r >> 5) + 4 * ((r >> 4) & 1) + 8 * ((r & 15) >> 2) + (r & 3);
    }

    // prologue: chunk 0 -> buffer 0
    #pragma unroll
    for (int j = 0; j < 2; j++) {
        int c = tid + j * 256;
        gload_lds16(Kbase + (size_t)kperm[j] * D3 + src_ch[j] * 8, Ks[0] + c * 8);
        gload_lds16(Vbase + (size_t)src_r[j] * Sq + src_ch[j] * 8, Vs[0] + c * 8);
    }

    for (int i = 0; i < 32; i++) {
        int cur = i & 1;
        __syncthreads();   // drains prefetch into buf[cur]; fences buf[cur^1] reuse
        if (i + 1 < 32) {  // prefetch next chunk; overlaps the whole compute below
            int k0 = (i + 1) * 64;
            bf16* kd = Ks[cur ^ 1];
            bf16* vd = Vs[cur ^ 1];
            #pragma unroll
            for (int j = 0; j < 2; j++) {
                int c = tid + j * 256;
                gload_lds16(Kbase + (size_t)(k0 + kperm[j]) * D3 + src_ch[j] * 8, kd + c * 8);
                gload_lds16(Vbase + (size_t)src_r[j] * Sq + k0 + src_ch[j] * 8, vd + c * 8);
            }
        }
        const bf16* K_ = Ks[cur];
        const bf16* V_ = Vs[cur];

        #pragma unroll
        for (int kt = 0; kt < 2; kt++) {   // 32-key tiles
            bfx4 plo[2], phi[2];
            // halftile 0: output keys 32kt + 8*quad + r
            {
                const bf16* Kh = K_ + (2 * kt) * 16 * 64;
                bfx8 k0f = *(const bfx8*)(Kh + l16 * 64 + (quad ^ sw) * 8);
                bfx8 k1f = *(const bfx8*)(Kh + l16 * 64 + ((4 + quad) ^ sw) * 8);
                #pragma unroll
                for (int qt = 0; qt < 2; qt++) {
                    f32x4 s = {};
                    s = MFMA_BF16(k0f, qf[qt][0], s, 0, 0, 0);
                    s = MFMA_BF16(k1f, qf[qt][1], s, 0, 0, 0);
                    #pragma unroll
                    for (int r = 0; r < 4; r++) {
                        float e = fast_exp2(s[r]);
                        plo[qt][r] = (bf16)e;
                        lsum[qt] += e;
                    }
                }
            }
            // halftile 1: output keys 32kt + 8*quad + 4 + r
            {
                const bf16* Kh = K_ + (2 * kt + 1) * 16 * 64;
                bfx8 k0f = *(const bfx8*)(Kh + l16 * 64 + (quad ^ sw) * 8);
                bfx8 k1f = *(const bfx8*)(Kh + l16 * 64 + ((4 + quad) ^ sw) * 8);
                #pragma unroll
                for (int qt = 0; qt < 2; qt++) {
                    f32x4 s = {};
                    s = MFMA_BF16(k0f, qf[qt][0], s, 0, 0, 0);
                    s = MFMA_BF16(k1f, qf[qt][1], s, 0, 0, 0);
                    #pragma unroll
                    for (int r = 0; r < 4; r++) {
                        float e = fast_exp2(s[r]);
                        phi[qt][r] = (bf16)e;
                        lsum[qt] += e;
                    }
                }
            }
            // P fragment (K=32 A-layout): keys 32kt + 8*quad + {0..7}
            bfx8 p8[2];
            #pragma unroll
            for (int qt = 0; qt < 2; qt++)
                p8[qt] = __builtin_shufflevector(plo[qt], phi[qt], 0, 1, 2, 3, 4, 5, 6, 7);

            // O += P V : B-frag = V^T[d = nt*16+l16][key = 32kt + 8*quad + j]
            #pragma unroll
            for (int nt = 0; nt < 4; nt++) {
                bfx8 vf = *(const bfx8*)(V_ + (nt * 16 + l16) * 64 +
                                         ((4 * kt + quad) ^ sw) * 8);
                #pragma unroll
                for (int qt = 0; qt < 2; qt++)
                    oacc[qt][nt] = MFMA_BF16(p8[qt], vf, oacc[qt][nt], 0, 0, 0);
            }
        }
    }

    // reduce row sums across quads: lane(*, l16) gets l[q = qt*16 + l16]
    float lfull[2];
    #pragma unroll
    for (int qt = 0; qt < 2; qt++) {
        float v = lsum[qt];
        v += __shfl_xor(v, 16);
        v += __shfl_xor(v, 32);
        lfull[qt] = v;
    }

    // epilogue: O rows are q = qt*16 + quad*4 + r; l fetched from lane (quad*4+r)
    #pragma unroll
    for (int qt = 0; qt < 2; qt++)
        #pragma unroll
        for (int r = 0; r < 4; r++) {
            int row = q0 + qt * 16 + quad * 4 + r;
            float inv = 1.0f / __shfl(lfull[qt], quad * 4 + r);
            #pragma unroll
            for (int nt = 0; nt < 4; nt++)
                out[((size_t)b * Sq + row) * Dq + h * HDq + nt * 16 + l16] =
                    (bf16)(oacc[qt][nt][r] * inv);
        }
}

extern "C" void kernel_launch(void* const* d_in, const int* in_sizes, int n_in,
                              void* d_out, int out_size, void* d_ws, size_t ws_size,
                              hipStream_t stream) {
    const float* x     = (const float*)d_in[0];
    const float* w_qkv = (const float*)d_in[1];
    const float* w_out = (const float*)d_in[2];
    float* out = (float*)d_out;

    char* ws = (char*)d_ws;
    bf16* x_bf   = (bf16*)ws;                                   // 16 MB (reused as Vt later)
    bf16* wqkvT  = (bf16*)(ws + 16777216);                      //  6 MB
    bf16* woutT  = (bf16*)(ws + 16777216 + 6291456);            //  2 MB
    bf16* qkv    = (bf16*)(ws + 16777216 + 6291456 + 2097152);  // 48 MB
    bf16* attn   = (bf16*)(ws + 16777216 + 6291456 + 2097152 + 50331648); // 16 MB
    bf16* Vt     = x_bf;   // x_bf dead after gemm1; reuse for V^T

    // 1. casts
    cast_f32_bf16<<<(Mq * Dq) / 4 / 256, 256, 0, stream>>>(x, x_bf, Mq * Dq);
    dim3 tb(32, 8);
    transpose_cast<<<dim3(D3 / 32, Dq / 32), tb, 0, stream>>>(w_qkv, wqkvT, Dq, D3);
    transpose_cast<<<dim3(Dq / 32, Dq / 32), tb, 0, stream>>>(w_out, woutT, Dq, Dq);

    // 2. qkv = x @ w_qkv   [8192 x 3072], Q columns pre-scaled by 0.125*log2(e)
    gemm_bt<false, true><<<dim3(D3 / 128, Mq / 128), 256, 0, stream>>>(x_bf, wqkvT, qkv, Mq, D3, Dq);

    // 3. V transpose (x_bf dead now)
    vtrans<<<dim3(Dq / 32, Sq / 32, Bq), tb, 0, stream>>>(qkv, Vt);

    // 4. attention (1024 blocks x 256 thr, XCD-affine, register-P, 16 waves/CU)
    attn_kernel<<<1024, 256, 0, stream>>>(qkv, Vt, attn);

    // 5. out = attn @ w_out  [8192 x 1024], fp32 out; 128x64 tiles -> 1024 blocks
    gemm_bt_n64<<<dim3(Dq / 64, Mq / 128), 256, 0, stream>>>(attn, woutT, out, Mq, Dq, Dq);
}